// Round 3
// baseline (705.203 us; speedup 1.0000x reference)
//
#include <hip/hip_runtime.h>
#include <math.h>

// Problem constants (fixed by setup_inputs): B=8, N=131072, C=76
#define N_PER   131072
#define NBATCH  8
#define REGC    76
#define TOTAL   (NBATCH * N_PER)      // 1,048,576
#define TILE    2048                  // elements per radix block
#define NBLKSEG 64                    // N_PER / TILE
#define BINS    256
#define HISTW   (NBATCH * BINS * NBLKSEG)   // words per pass-histogram

// ---------------------------------------------------------------------------
// key transform: float -> uint such that ascending uint sort == descending
// float sort; stable LSD radix then matches stable jnp.argsort(-scores).
__device__ __forceinline__ unsigned desc_key(float f) {
    unsigned u = __float_as_uint(f);
    return (u & 0x80000000u) ? u : ~(u | 0x80000000u);
}

// ---------------------------------------------------------------------------
// Stage 1: decode boxes + keys/payloads + fused pass-0 histogram.
// 128 threads / 128 rows per block; rows staged via LDS so global loads are
// perfectly coalesced float4s. LDS row stride 77 dwords (13 coprime 32 ->
// conflict-free per-thread row reads).
__global__ __launch_bounds__(128) void decode_kernel(
    const float* __restrict__ scores, const float* __restrict__ reg,
    const float* __restrict__ xyz, const float* __restrict__ anchor,
    float* __restrict__ boxes8, unsigned* __restrict__ keyA,
    unsigned* __restrict__ payA, unsigned* __restrict__ hist0)
{
    __shared__ float lds[128 * 77];   // 39,424 B
    int tid = threadIdx.x;
    int p = blockIdx.x * 128 + tid;   // this thread's row

    // ---- coalesced stage: 128 rows * 19 float4 = 2432 float4 per block
    const float4* g4 = (const float4*)(reg + (size_t)blockIdx.x * 128 * REGC);
#pragma unroll
    for (int j = 0; j < 19; ++j) {
        int f = j * 128 + tid;        // float4 index within block
        int row = f / 19, col = f - row * 19;
        float4 v = g4[f];
        float* dst = &lds[row * 77 + col * 4];
        dst[0] = v.x; dst[1] = v.y; dst[2] = v.z; dst[3] = v.w;
    }
    __syncthreads();

    const float* r = &lds[tid * 77];

    int xb = 0; float xm = r[0];
#pragma unroll
    for (int c = 1; c < 12; ++c) { float v = r[c];      if (v > xm) { xm = v; xb = c; } }
    int zb = 0; float zm = r[12];
#pragma unroll
    for (int c = 1; c < 12; ++c) { float v = r[12 + c]; if (v > zm) { zm = v; zb = c; } }
    int yb = 0; float ym = r[49];
#pragma unroll
    for (int c = 1; c < 12; ++c) { float v = r[49 + c]; if (v > ym) { ym = v; yb = c; } }

    float x_res  = r[24 + xb];
    float z_res  = r[36 + zb];
    float ry_res = r[61 + yb];

    float rx  = xyz[(size_t)p * 3 + 0];
    float ryy = xyz[(size_t)p * 3 + 1];
    float rz  = xyz[(size_t)p * 3 + 2];
    float a0 = anchor[0], a1 = anchor[1], a2 = anchor[2];

    const float APC    = (float)(2.0 * M_PI / 12.0);
    const float HAPC   = (float)(M_PI / 12.0);
    const float TWO_PI = (float)(2.0 * M_PI);
    const float PI_F   = (float)M_PI;

    // heading: replicate jnp.remainder == fmodf then +2pi if negative.
    float vry = __fadd_rn(__fmul_rn((float)yb, APC), __fmul_rn(ry_res, HAPC));
    float m = fmodf(vry, TWO_PI);
    if (m < 0.0f) m += TWO_PI;
    if (m > PI_F) m -= TWO_PI;

    float h = r[73] * a0 + a0;
    float w = r[74] * a1 + a1;
    float l = r[75] * a2 + a2;

    float ox = (((float)xb * 0.5f + 0.25f - 3.0f) + x_res * 0.5f) + rx;
    float oz = (((float)zb * 0.5f + 0.25f - 3.0f) + z_res * 0.5f) + rz;
    float oy = (ryy + r[48]) + h * 0.5f;   // post_process: y + h/2

    float sc = scores[p];

    float4* ob = (float4*)(boxes8 + (size_t)p * 8);
    ob[0] = make_float4(ox, oy, oz, h);
    ob[1] = make_float4(w, l, m, sc);

    unsigned key = desc_key(sc);
    keyA[p] = key;
    payA[p] = (unsigned)(p & (N_PER - 1));

    // fused pass-0 histogram (TILE decomposition of the linear layout)
    int seg = p >> 17;
    int blk = (p & (N_PER - 1)) >> 11;            // TILE = 2048
    atomicAdd(&hist0[(size_t)(seg * BINS + (key & 255u)) * NBLKSEG + blk], 1u);
}

// ---------------------------------------------------------------------------
// Per-segment scan: hist[seg][bin][blk] -> within-segment exclusive offsets.
__global__ __launch_bounds__(256) void scan_kernel(unsigned* __restrict__ hist)
{
    int seg = blockIdx.x, bin = threadIdx.x;
    uint4* hp = (uint4*)(hist + (size_t)(seg * BINS + bin) * NBLKSEG);
    unsigned run = 0;
#pragma unroll
    for (int i = 0; i < NBLKSEG / 4; ++i) {
        uint4 v = hp[i];
        uint4 o;
        o.x = run; o.y = o.x + v.x; o.z = o.y + v.y; o.w = o.z + v.z;
        run = o.w + v.w;
        hp[i] = o;
    }
    __shared__ unsigned sc[BINS];
    sc[bin] = run;
    __syncthreads();
    for (int off = 1; off < BINS; off <<= 1) {
        unsigned v = (bin >= off) ? sc[bin - off] : 0u;
        __syncthreads();
        sc[bin] += v;
        __syncthreads();
    }
    unsigned excl = sc[bin] - run;
#pragma unroll
    for (int i = 0; i < NBLKSEG / 4; ++i) {
        uint4 o = hp[i];
        o.x += excl; o.y += excl; o.z += excl; o.w += excl;
        hp[i] = o;
    }
}

// ---------------------------------------------------------------------------
// Stable scatter (ballot-ranked). !FINAL: writes key/pay + fused next-pass
// histogram. FINAL: writes output rows directly (fused gather).
template <int SHIFT, bool FINAL>
__global__ __launch_bounds__(256) void scatter_kernel(
    const unsigned* __restrict__ keyIn, const unsigned* __restrict__ payIn,
    unsigned* __restrict__ keyOut, unsigned* __restrict__ payOut,
    const unsigned* __restrict__ hist, unsigned* __restrict__ histNext,
    const float* __restrict__ boxes8, float* __restrict__ out)
{
    __shared__ unsigned offs[BINS];
    __shared__ unsigned running[BINS];
    __shared__ unsigned whist[4][BINS];
    int tid = threadIdx.x;
    int seg = blockIdx.y, blk = blockIdx.x;
    int wave = tid >> 6, lane = tid & 63;
    unsigned long long lmask = (1ull << lane) - 1ull;

    offs[tid] = hist[(size_t)(seg * BINS + tid) * NBLKSEG + blk];
    running[tid] = 0;
#pragma unroll
    for (int w2 = 0; w2 < 4; ++w2) whist[w2][tid] = 0;

    const unsigned* ki = keyIn + (size_t)seg * N_PER + (size_t)blk * TILE;
    const unsigned* pi = payIn + (size_t)seg * N_PER + (size_t)blk * TILE;

    for (int c = 0; c < TILE / 256; ++c) {
        __syncthreads();   // whist zeroed + running updated from prev chunk
        unsigned key = ki[c * 256 + tid];
        unsigned pay = pi[c * 256 + tid];
        unsigned d = (key >> SHIFT) & 255u;
        unsigned long long peers = ~0ull;
#pragma unroll
        for (int b = 0; b < 8; ++b) {
            unsigned long long vote = __ballot((d >> b) & 1u);
            peers &= ((d >> b) & 1u) ? vote : ~vote;
        }
        unsigned rank = (unsigned)__popcll(peers & lmask);
        unsigned cnt  = (unsigned)__popcll(peers);
        if (rank == 0) whist[wave][d] = cnt;
        __syncthreads();
        unsigned prefix = running[d];
#pragma unroll
        for (int w2 = 0; w2 < 4; ++w2) { if (w2 < wave) prefix += whist[w2][d]; }
        unsigned pos = offs[d] + prefix + rank;

        if (FINAL) {
            // fused gather: write the output row directly
            const float4* src = (const float4*)(boxes8 +
                                ((size_t)(seg * N_PER) + pay) * 8);
            float4 v0 = src[0], v1 = src[1];
            float4* dst = (float4*)(out + ((size_t)(seg * N_PER) + pos) * 8);
            dst[0] = v0; dst[1] = v1;
        } else {
            unsigned* ko = keyOut + (size_t)seg * N_PER;
            unsigned* po = payOut + (size_t)seg * N_PER;
            ko[pos] = key;
            po[pos] = pay;
            unsigned nd = (key >> (SHIFT + 8)) & 255u;
            atomicAdd(&histNext[(size_t)(seg * BINS + nd) * NBLKSEG + (pos >> 11)], 1u);
        }
        __syncthreads();   // all reads of running/whist done
        unsigned sum = whist[0][tid] + whist[1][tid] + whist[2][tid] + whist[3][tid];
        running[tid] += sum;
        whist[0][tid] = 0; whist[1][tid] = 0; whist[2][tid] = 0; whist[3][tid] = 0;
    }
}

// ---------------------------------------------------------------------------
extern "C" void kernel_launch(void* const* d_in, const int* in_sizes, int n_in,
                              void* d_out, int out_size, void* d_ws, size_t ws_size,
                              hipStream_t stream)
{
    const float* scores = (const float*)d_in[0];
    const float* reg    = (const float*)d_in[1];
    const float* xyz    = (const float*)d_in[2];
    const float* anchor = (const float*)d_in[3];
    float* out = (float*)d_out;

    // workspace carve-up (~51.6 MB)
    char* ws = (char*)d_ws;
    float*    boxes8 = (float*)ws;
    size_t    off    = (size_t)TOTAL * 8 * sizeof(float);
    unsigned* keyA = (unsigned*)(ws + off); off += (size_t)TOTAL * 4;
    unsigned* payA = (unsigned*)(ws + off); off += (size_t)TOTAL * 4;
    unsigned* keyB = (unsigned*)(ws + off); off += (size_t)TOTAL * 4;
    unsigned* payB = (unsigned*)(ws + off); off += (size_t)TOTAL * 4;
    unsigned* histAll = (unsigned*)(ws + off); off += (size_t)4 * HISTW * 4;
    unsigned* h0 = histAll;
    unsigned* h1 = histAll + HISTW;
    unsigned* h2 = histAll + 2 * (size_t)HISTW;
    unsigned* h3 = histAll + 3 * (size_t)HISTW;
    (void)ws_size; (void)in_sizes; (void)n_in; (void)out_size;

    // zero all 4 pass-histograms (they are accumulated via atomics)
    hipMemsetAsync(histAll, 0, (size_t)4 * HISTW * 4, stream);

    decode_kernel<<<TOTAL / 128, 128, 0, stream>>>(scores, reg, xyz, anchor,
                                                   boxes8, keyA, payA, h0);

    dim3 sg(NBLKSEG, NBATCH);
    scan_kernel<<<NBATCH, 256, 0, stream>>>(h0);
    scatter_kernel<0,  false><<<sg, 256, 0, stream>>>(keyA, payA, keyB, payB,
                                                      h0, h1, nullptr, nullptr);
    scan_kernel<<<NBATCH, 256, 0, stream>>>(h1);
    scatter_kernel<8,  false><<<sg, 256, 0, stream>>>(keyB, payB, keyA, payA,
                                                      h1, h2, nullptr, nullptr);
    scan_kernel<<<NBATCH, 256, 0, stream>>>(h2);
    scatter_kernel<16, false><<<sg, 256, 0, stream>>>(keyA, payA, keyB, payB,
                                                      h2, h3, nullptr, nullptr);
    scan_kernel<<<NBATCH, 256, 0, stream>>>(h3);
    scatter_kernel<24, true ><<<sg, 256, 0, stream>>>(keyB, payB, nullptr, nullptr,
                                                      h3, nullptr, boxes8, out);
}